// Round 6
// baseline (1156.957 us; speedup 1.0000x reference)
//
#include <hip/hip_runtime.h>

#define NN 100000
#define NE 3200000
#define NR 8
#define NBUK 6250            // dst>>4 buckets (16 nodes each)
#define NCH 50               // edge-index chunks per bucket
#define CHSZ 64000           // NE / NCH exactly
#define NKC (NBUK * NCH)     // 312500 cells
#define SCAN_TPB 256
#define SCAN_EPB 1024
#define NB ((NKC + SCAN_EPB - 1) / SCAN_EPB)   // 306 blocks

// ---------- chunked coarse histogram: cell = (dst>>4)*NCH + e/CHSZ ----------
__global__ void chunk_hist(const int* __restrict__ dst, int* __restrict__ ccnt) {
    int e = blockIdx.x * blockDim.x + threadIdx.x;
    if (e < NE) {
        int cell = (dst[e] >> 4) * NCH + e / CHSZ;
        atomicAdd(&ccnt[cell], 1);
    }
}

// ---------- 3-kernel exclusive scan over ccnt[NKC] -> coff[NKC] ----------
__global__ void block_sums(const int* __restrict__ cnt, int* __restrict__ bsum) {
    __shared__ int s[SCAN_TPB];
    int base = blockIdx.x * SCAN_EPB;
    int t = threadIdx.x;
    int v = 0;
#pragma unroll
    for (int j = 0; j < 4; j++) {
        int idx = base + t * 4 + j;
        if (idx < NKC) v += cnt[idx];
    }
    s[t] = v; __syncthreads();
    for (int o = SCAN_TPB / 2; o > 0; o >>= 1) {
        if (t < o) s[t] += s[t + o];
        __syncthreads();
    }
    if (t == 0) bsum[blockIdx.x] = s[0];
}

__global__ void scan_sums(int* __restrict__ bsum) {  // single block, 1024 threads
    __shared__ int s[1024];
    int t = threadIdx.x;
    int v = (t < NB) ? bsum[t] : 0;
    s[t] = v; __syncthreads();
    for (int o = 1; o < 1024; o <<= 1) {
        int u = (t >= o) ? s[t - o] : 0;
        __syncthreads();
        s[t] += u;
        __syncthreads();
    }
    if (t < NB) bsum[t] = s[t] - v;  // exclusive
}

__global__ void block_scan(const int* __restrict__ cnt, const int* __restrict__ bsum,
                           int* __restrict__ off) {
    __shared__ int s[SCAN_TPB];
    int base = blockIdx.x * SCAN_EPB;
    int t = threadIdx.x;
    int v[4]; int sum = 0;
#pragma unroll
    for (int j = 0; j < 4; j++) {
        int idx = base + t * 4 + j;
        v[j] = (idx < NKC) ? cnt[idx] : 0;
        sum += v[j];
    }
    s[t] = sum; __syncthreads();
    int mine = sum;
    for (int o = 1; o < SCAN_TPB; o <<= 1) {
        int u = (t >= o) ? s[t - o] : 0;
        __syncthreads();
        s[t] += u;
        __syncthreads();
    }
    int ex = s[t] - mine + bsum[blockIdx.x];
#pragma unroll
    for (int j = 0; j < 4; j++) {
        int idx = base + t * 4 + j;
        if (idx < NKC) { off[idx] = ex; ex += v[j]; }
    }
}

// ---------- pass 1: scatter packed (dst&15)<<20 | et<<17 | src into cells ----------
__global__ void pass1(const int* __restrict__ src, const int* __restrict__ dst,
                      const int* __restrict__ et, const int* __restrict__ coff,
                      int* __restrict__ cfill, unsigned* __restrict__ pk) {
    int e = blockIdx.x * blockDim.x + threadIdx.x;
    if (e >= NE) return;
    int d = dst[e];
    int cell = (d >> 4) * NCH + e / CHSZ;
    int pos = coff[cell] + atomicAdd(&cfill[cell], 1);
    pk[pos] = ((unsigned)(d & 15) << 20) | ((unsigned)et[e] << 17) | (unsigned)src[e];
}

// ---------- Layer 1 direct: LDS-atomic aggregate + root + matmuls + ReLU ----------
// one block per 16-node bucket; 256 threads = 16 edge-slots x 16 feature-lanes
__global__ __launch_bounds__(256, 8) void l1_direct(
        const float* __restrict__ x, const unsigned* __restrict__ pk,
        const int* __restrict__ coff,
        const float* __restrict__ W1, const float* __restrict__ root1,
        const float* __restrict__ b1, float* __restrict__ h) {
    __shared__ float sAgg[16][NR][17];   // pad 17 to spread banks
    __shared__ int   sCnt[16][NR];
    int t = threadIdx.x;
    {
        float* p = &sAgg[0][0][0];
        for (int i = t; i < 16 * NR * 17; i += 256) p[i] = 0.0f;
        if (t < 16 * NR) sCnt[t >> 3][t & 7] = 0;
    }
    __syncthreads();
    int b = blockIdx.x;
    int s0 = coff[b * NCH];
    int e1 = (b == NBUK - 1) ? NE : coff[(b + 1) * NCH];
    int slot = t >> 4, k = t & 15;
    for (int e = s0 + slot; e < e1; e += 16) {
        unsigned u = pk[e];
        int d = (u >> 20) & 15;
        int r = (u >> 17) & 7;
        int j = u & 0x1FFFF;
        float v = x[j * 16 + k];
        atomicAdd(&sAgg[d][r][k], v);
        if (k == 0) atomicAdd(&sCnt[d][r], 1);
    }
    __syncthreads();
    // scale by 1/max(cnt,1)
    for (int idx = t; idx < 16 * NR * 16; idx += 256) {
        int d = idx >> 7, rr = (idx >> 4) & 7, kk = idx & 15;
        int c = sCnt[d][rr];
        sAgg[d][rr][kk] *= (1.0f / (float)(c > 1 ? c : 1));
    }
    __syncthreads();
    // 512 outputs (16 nodes x 32), 2 per thread; W1/root1/b1 via L1 (hot)
#pragma unroll
    for (int ph = 0; ph < 2; ph++) {
        int idx = ph * 256 + t;
        int n2 = idx >> 5, o = idx & 31;
        int ii = b * 16 + n2;
        float a = b1[o];
        const float* xi = x + ii * 16;
#pragma unroll
        for (int kk = 0; kk < 16; kk++) a += xi[kk] * root1[kk * 32 + o];
#pragma unroll
        for (int r = 0; r < NR; r++)
#pragma unroll
            for (int kk = 0; kk < 16; kk++)
                a += sAgg[n2][r][kk] * W1[(r * 16 + kk) * 32 + o];
        h[ii * 32 + o] = fmaxf(a, 0.0f);
    }
}

// ---------- Layer 2 direct: LDS-atomic aggregate + root2 + matmuls ----------
// one block per 16-node bucket; 256 threads = 8 edge-slots x 32 feature-lanes
__global__ __launch_bounds__(256, 8) void l2_direct(
        const float* __restrict__ hbuf, const unsigned* __restrict__ pk,
        const int* __restrict__ coff,
        const float* __restrict__ W2, const float* __restrict__ root2,
        const float* __restrict__ b2, float* __restrict__ out) {
    __shared__ float sAgg[16][NR][33];   // pad 33 to spread banks (~16.9 KB)
    __shared__ int   sCnt[16][NR];
    int t = threadIdx.x;
    {
        float* p = &sAgg[0][0][0];
        for (int i = t; i < 16 * NR * 33; i += 256) p[i] = 0.0f;
        if (t < 16 * NR) sCnt[t >> 3][t & 7] = 0;
    }
    __syncthreads();
    int b = blockIdx.x;
    int s0 = coff[b * NCH];
    int e1 = (b == NBUK - 1) ? NE : coff[(b + 1) * NCH];
    int slot = t >> 5, k = t & 31;
    for (int e = s0 + slot; e < e1; e += 8) {
        unsigned u = pk[e];
        int d = (u >> 20) & 15;
        int r = (u >> 17) & 7;
        int j = u & 0x1FFFF;
        float v = hbuf[j * 32 + k];
        atomicAdd(&sAgg[d][r][k], v);
        if (k == 0) atomicAdd(&sCnt[d][r], 1);
    }
    __syncthreads();
    // scale by 1/max(cnt,1)
    for (int idx = t; idx < 16 * NR * 32; idx += 256) {
        int d = idx >> 8, rr = (idx >> 5) & 7, kk = idx & 31;
        int c = sCnt[d][rr];
        sAgg[d][rr][kk] *= (1.0f / (float)(c > 1 ? c : 1));
    }
    __syncthreads();
    // 256 outputs (16 nodes x 16), 1 per thread; W2/root2/b2 via L1 (hot)
    int n2 = t >> 4, o = t & 15;
    int ii = b * 16 + n2;
    float a = b2[o];
    const float* hi = hbuf + ii * 32;
#pragma unroll
    for (int kk = 0; kk < 32; kk++) a += hi[kk] * root2[kk * 16 + o];
#pragma unroll
    for (int r = 0; r < NR; r++)
#pragma unroll
        for (int kk = 0; kk < 32; kk++)
            a += sAgg[n2][r][kk] * W2[(r * 32 + kk) * 16 + o];
    out[ii * 16 + o] = a;
}

extern "C" void kernel_launch(void* const* d_in, const int* in_sizes, int n_in,
                              void* d_out, int out_size, void* d_ws, size_t ws_size,
                              hipStream_t stream) {
    const float* x = (const float*)d_in[0];
    const int* ei = (const int*)d_in[1];
    const int* et = (const int*)d_in[2];
    const float* W1 = (const float*)d_in[3];
    const float* root1 = (const float*)d_in[4];
    const float* b1 = (const float*)d_in[5];
    const float* W2 = (const float*)d_in[6];
    const float* root2 = (const float*)d_in[7];
    const float* b2 = (const float*)d_in[8];
    float* out = (float*)d_out;
    const int* src = ei;
    const int* dst = ei + NE;

    char* ws = (char*)d_ws;
    int* ccnt      = (int*)(ws + 0);            // 1.25 MB
    int* cfill     = (int*)(ws + 1250000);      // 1.25 MB
    int* coff      = (int*)(ws + 2500000);      // 1.25 MB
    int* bsum      = (int*)(ws + 3750000);      // ~1.3 KB
    unsigned* pk   = (unsigned*)(ws + 3754096); // 12.8 MB
    float* h       = (float*)(ws + 16554096);   // 12.8 MB  (total ~29.4 MB)

    const int TPB = 256;
    hipMemsetAsync(ccnt, 0, 2500000, stream);   // ccnt + cfill (contiguous)
    chunk_hist<<<(NE + TPB - 1) / TPB, TPB, 0, stream>>>(dst, ccnt);
    block_sums<<<NB, SCAN_TPB, 0, stream>>>(ccnt, bsum);
    scan_sums<<<1, 1024, 0, stream>>>(bsum);
    block_scan<<<NB, SCAN_TPB, 0, stream>>>(ccnt, bsum, coff);
    pass1<<<(NE + TPB - 1) / TPB, TPB, 0, stream>>>(src, dst, et, coff, cfill, pk);
    l1_direct<<<NBUK, 256, 0, stream>>>(x, pk, coff, W1, root1, b1, h);
    l2_direct<<<NBUK, 256, 0, stream>>>(h, pk, coff, W2, root2, b2, out);
}

// Round 7
// 1150.082 us; speedup vs baseline: 1.0060x; 1.0060x over previous
//
#include <hip/hip_runtime.h>

#define NN 100000
#define NE 3200000
#define NR 8
#define NBUK 6250            // dst>>4 buckets (16 nodes each)
#define NCH 50               // edge-index chunks per bucket
#define CHSZ 64000           // NE / NCH exactly
#define NKC (NBUK * NCH)     // 312500 cells
#define SCAN_TPB 256
#define SCAN_EPB 1024
#define NB ((NKC + SCAN_EPB - 1) / SCAN_EPB)   // 306 blocks

// ---------- chunked coarse histogram: cell = (dst>>4)*NCH + e/CHSZ ----------
__global__ void chunk_hist(const int* __restrict__ dst, int* __restrict__ ccnt) {
    int e = blockIdx.x * blockDim.x + threadIdx.x;
    if (e < NE) {
        int cell = (dst[e] >> 4) * NCH + e / CHSZ;
        atomicAdd(&ccnt[cell], 1);
    }
}

// ---------- 3-kernel exclusive scan over ccnt[NKC] -> coff[NKC] ----------
__global__ void block_sums(const int* __restrict__ cnt, int* __restrict__ bsum) {
    __shared__ int s[SCAN_TPB];
    int base = blockIdx.x * SCAN_EPB;
    int t = threadIdx.x;
    int v = 0;
#pragma unroll
    for (int j = 0; j < 4; j++) {
        int idx = base + t * 4 + j;
        if (idx < NKC) v += cnt[idx];
    }
    s[t] = v; __syncthreads();
    for (int o = SCAN_TPB / 2; o > 0; o >>= 1) {
        if (t < o) s[t] += s[t + o];
        __syncthreads();
    }
    if (t == 0) bsum[blockIdx.x] = s[0];
}

__global__ void scan_sums(int* __restrict__ bsum) {  // single block, 1024 threads
    __shared__ int s[1024];
    int t = threadIdx.x;
    int v = (t < NB) ? bsum[t] : 0;
    s[t] = v; __syncthreads();
    for (int o = 1; o < 1024; o <<= 1) {
        int u = (t >= o) ? s[t - o] : 0;
        __syncthreads();
        s[t] += u;
        __syncthreads();
    }
    if (t < NB) bsum[t] = s[t] - v;  // exclusive
}

__global__ void block_scan(const int* __restrict__ cnt, const int* __restrict__ bsum,
                           int* __restrict__ off) {
    __shared__ int s[SCAN_TPB];
    int base = blockIdx.x * SCAN_EPB;
    int t = threadIdx.x;
    int v[4]; int sum = 0;
#pragma unroll
    for (int j = 0; j < 4; j++) {
        int idx = base + t * 4 + j;
        v[j] = (idx < NKC) ? cnt[idx] : 0;
        sum += v[j];
    }
    s[t] = sum; __syncthreads();
    int mine = sum;
    for (int o = 1; o < SCAN_TPB; o <<= 1) {
        int u = (t >= o) ? s[t - o] : 0;
        __syncthreads();
        s[t] += u;
        __syncthreads();
    }
    int ex = s[t] - mine + bsum[blockIdx.x];
#pragma unroll
    for (int j = 0; j < 4; j++) {
        int idx = base + t * 4 + j;
        if (idx < NKC) { off[idx] = ex; ex += v[j]; }
    }
}

// ---------- pass 1: scatter packed (dst&15)<<20 | et<<17 | src into cells ----------
__global__ void pass1(const int* __restrict__ src, const int* __restrict__ dst,
                      const int* __restrict__ et, const int* __restrict__ coff,
                      int* __restrict__ cfill, unsigned* __restrict__ pk) {
    int e = blockIdx.x * blockDim.x + threadIdx.x;
    if (e >= NE) return;
    int d = dst[e];
    int cell = (d >> 4) * NCH + e / CHSZ;
    int pos = coff[cell] + atomicAdd(&cfill[cell], 1);
    pk[pos] = ((unsigned)(d & 15) << 20) | ((unsigned)et[e] << 17) | (unsigned)src[e];
}

// ---------- pass 2: per-bucket fine sort by node; epk + CSR off + (node,rel) counts ----
__global__ __launch_bounds__(256) void pass2(const unsigned* __restrict__ pk,
                                             const int* __restrict__ coff,
                                             unsigned* __restrict__ epk,
                                             int* __restrict__ off,
                                             int* __restrict__ cnt_nr) {
    __shared__ int lcnt2[16][NR];
    __shared__ int lrow[16];
    __shared__ int lfill[16];
    __shared__ int lscan[16];
    int b = blockIdx.x, t = threadIdx.x;
    int base = coff[b * NCH];
    int end = (b == NBUK - 1) ? NE : coff[(b + 1) * NCH];
    if (t < 128) lcnt2[t >> 3][t & 7] = 0;
    if (t < 16) lfill[t] = 0;
    __syncthreads();
    for (int e = base + t; e < end; e += 256) {
        unsigned u = pk[e];
        atomicAdd(&lcnt2[u >> 20][(u >> 17) & 7], 1);
    }
    __syncthreads();
    if (t < 16) {
        int s = 0;
#pragma unroll
        for (int r = 0; r < NR; r++) s += lcnt2[t][r];
        lrow[t] = s;
    }
    if (t < 128) cnt_nr[b * 128 + t] = lcnt2[t >> 3][t & 7];
    __syncthreads();
    if (t == 0) {
        int run = 0;
        for (int d = 0; d < 16; d++) {
            lscan[d] = run;
            off[b * 16 + d] = base + run;
            run += lrow[d];
        }
        if (b == NBUK - 1) off[NN] = NE;
    }
    __syncthreads();
    for (int e = base + t; e < end; e += 256) {
        unsigned u = pk[e];
        int d = u >> 20;
        int p = atomicAdd(&lfill[d], 1);
        epk[base + lscan[d] + p] = u;
    }
}

// ---------- Layer 1 fused: gather + LDS-atomic rel-accumulate + root + matmuls + ReLU
// block = 256 threads = 16 nodes x 16 feature-lanes
__global__ __launch_bounds__(256, 8) void l1_fused(
        const float* __restrict__ x, const unsigned* __restrict__ epk,
        const int* __restrict__ off, const int* __restrict__ cnt_nr,
        const float* __restrict__ W1, const float* __restrict__ root1,
        const float* __restrict__ b1, float* __restrict__ h) {
    __shared__ float sAgg[16][NR][17];   // 8.7 KB; k-lanes spread banks, pad rows
    int t = threadIdx.x;
    {
        float* p = &sAgg[0][0][0];
        for (int i2 = t; i2 < 16 * NR * 17; i2 += 256) p[i2] = 0.0f;
    }
    __syncthreads();
    int nl = t >> 4, k = t & 15;
    int i = blockIdx.x * 16 + nl;
    int s0 = off[i], e1 = off[i + 1];
    int e0 = s0;
    for (; e0 + 4 <= e1; e0 += 4) {
        unsigned u0 = epk[e0 + 0];
        unsigned u1 = epk[e0 + 1];
        unsigned u2 = epk[e0 + 2];
        unsigned u3 = epk[e0 + 3];
        float v0 = x[(u0 & 0x1FFFF) * 16 + k];
        float v1 = x[(u1 & 0x1FFFF) * 16 + k];
        float v2 = x[(u2 & 0x1FFFF) * 16 + k];
        float v3 = x[(u3 & 0x1FFFF) * 16 + k];
        atomicAdd(&sAgg[nl][(u0 >> 17) & 7][k], v0);
        atomicAdd(&sAgg[nl][(u1 >> 17) & 7][k], v1);
        atomicAdd(&sAgg[nl][(u2 >> 17) & 7][k], v2);
        atomicAdd(&sAgg[nl][(u3 >> 17) & 7][k], v3);
    }
    for (; e0 < e1; e0++) {
        unsigned u = epk[e0];
        atomicAdd(&sAgg[nl][(u >> 17) & 7][k], x[(u & 0x1FFFF) * 16 + k]);
    }
    __syncthreads();
    // scale by 1/max(cnt,1): 16 nodes x 8 rels x 16 k = 2048 elements
    for (int idx = t; idx < 16 * NR * 16; idx += 256) {
        int d = idx >> 7, rr = (idx >> 4) & 7, kk = idx & 15;
        int c = cnt_nr[(blockIdx.x * 16 + d) * 8 + rr];
        sAgg[d][rr][kk] *= (1.0f / (float)(c > 1 ? c : 1));
    }
    __syncthreads();
    // 512 outputs (16 nodes x 32), 2 per thread; W1/root1/b1 via L1 (hot)
#pragma unroll
    for (int ph = 0; ph < 2; ph++) {
        int idx = ph * 256 + t;
        int n2 = idx >> 5, o = idx & 31;
        int ii = blockIdx.x * 16 + n2;
        float a = b1[o];
        const float* xi = x + ii * 16;
#pragma unroll
        for (int kk = 0; kk < 16; kk++) a += xi[kk] * root1[kk * 32 + o];
#pragma unroll
        for (int r = 0; r < NR; r++)
#pragma unroll
            for (int kk = 0; kk < 16; kk++)
                a += sAgg[n2][r][kk] * W1[(r * 16 + kk) * 32 + o];
        h[ii * 32 + o] = fmaxf(a, 0.0f);
    }
}

// ---------- Layer 2 fused: gather + LDS-atomic rel-accumulate + root2 + matmuls ----
// block = 256 threads = 8 nodes x 32 feature-lanes
__global__ __launch_bounds__(256, 8) void l2_fused(
        const float* __restrict__ h, const unsigned* __restrict__ epk,
        const int* __restrict__ off, const int* __restrict__ cnt_nr,
        const float* __restrict__ W2, const float* __restrict__ root2,
        const float* __restrict__ b2, float* __restrict__ out) {
    __shared__ float sAgg[8][NR][33];    // 8.4 KB; pad 33
    int t = threadIdx.x;
    {
        float* p = &sAgg[0][0][0];
        for (int i2 = t; i2 < 8 * NR * 33; i2 += 256) p[i2] = 0.0f;
    }
    __syncthreads();
    int nl = t >> 5, k = t & 31;
    int i = blockIdx.x * 8 + nl;
    int s0 = off[i], e1 = off[i + 1];
    int e0 = s0;
    for (; e0 + 4 <= e1; e0 += 4) {
        unsigned u0 = epk[e0 + 0];
        unsigned u1 = epk[e0 + 1];
        unsigned u2 = epk[e0 + 2];
        unsigned u3 = epk[e0 + 3];
        float v0 = h[(u0 & 0x1FFFF) * 32 + k];
        float v1 = h[(u1 & 0x1FFFF) * 32 + k];
        float v2 = h[(u2 & 0x1FFFF) * 32 + k];
        float v3 = h[(u3 & 0x1FFFF) * 32 + k];
        atomicAdd(&sAgg[nl][(u0 >> 17) & 7][k], v0);
        atomicAdd(&sAgg[nl][(u1 >> 17) & 7][k], v1);
        atomicAdd(&sAgg[nl][(u2 >> 17) & 7][k], v2);
        atomicAdd(&sAgg[nl][(u3 >> 17) & 7][k], v3);
    }
    for (; e0 < e1; e0++) {
        unsigned u = epk[e0];
        atomicAdd(&sAgg[nl][(u >> 17) & 7][k], h[(u & 0x1FFFF) * 32 + k]);
    }
    __syncthreads();
    // scale: 8 nodes x 8 rels x 32 k = 2048 elements
    for (int idx = t; idx < 8 * NR * 32; idx += 256) {
        int d = idx >> 8, rr = (idx >> 5) & 7, kk = idx & 31;
        int c = cnt_nr[(blockIdx.x * 8 + d) * 8 + rr];
        sAgg[d][rr][kk] *= (1.0f / (float)(c > 1 ? c : 1));
    }
    __syncthreads();
    // per node: 16 outputs, k-sum split across lane halves; W2/root2/b2 via L1
    int o = k & 15, half = k >> 4;
    float a = 0.0f;
    const float* hi = h + i * 32;
#pragma unroll
    for (int kk = 0; kk < 16; kk++) {
        int kf = half * 16 + kk;
        a += hi[kf] * root2[kf * 16 + o];
    }
#pragma unroll
    for (int r = 0; r < NR; r++)
#pragma unroll
        for (int kk = 0; kk < 16; kk++) {
            int kf = half * 16 + kk;
            a += sAgg[nl][r][kf] * W2[(r * 32 + kf) * 16 + o];
        }
    float tot = a + __shfl_xor(a, 16);
    if (half == 0) out[i * 16 + o] = tot + b2[o];
}

extern "C" void kernel_launch(void* const* d_in, const int* in_sizes, int n_in,
                              void* d_out, int out_size, void* d_ws, size_t ws_size,
                              hipStream_t stream) {
    const float* x = (const float*)d_in[0];
    const int* ei = (const int*)d_in[1];
    const int* et = (const int*)d_in[2];
    const float* W1 = (const float*)d_in[3];
    const float* root1 = (const float*)d_in[4];
    const float* b1 = (const float*)d_in[5];
    const float* W2 = (const float*)d_in[6];
    const float* root2 = (const float*)d_in[7];
    const float* b2 = (const float*)d_in[8];
    float* out = (float*)d_out;
    const int* src = ei;
    const int* dst = ei + NE;

    char* ws = (char*)d_ws;
    int* off       = (int*)(ws + 0);            // (NN+1)*4 = 400,004 B
    int* ccnt      = (int*)(ws + 400016);       // 1.25 MB
    int* cfill     = (int*)(ws + 1650016);      // 1.25 MB
    int* coff      = (int*)(ws + 2900016);      // 1.25 MB
    int* bsum      = (int*)(ws + 4150016);      // ~1.3 KB
    unsigned* pk   = (unsigned*)(ws + 4154112); // 12.8 MB
    unsigned* epk  = (unsigned*)(ws + 16954112);// 12.8 MB
    float* h       = (float*)(ws + 29754112);   // 12.8 MB
    int* cnt_nr    = (int*)(ws + 42554112);     // 3.2 MB  (total ~45.8 MB)

    const int TPB = 256;
    hipMemsetAsync(ccnt, 0, 2500000, stream);   // ccnt + cfill (contiguous)
    chunk_hist<<<(NE + TPB - 1) / TPB, TPB, 0, stream>>>(dst, ccnt);
    block_sums<<<NB, SCAN_TPB, 0, stream>>>(ccnt, bsum);
    scan_sums<<<1, 1024, 0, stream>>>(bsum);
    block_scan<<<NB, SCAN_TPB, 0, stream>>>(ccnt, bsum, coff);
    pass1<<<(NE + TPB - 1) / TPB, TPB, 0, stream>>>(src, dst, et, coff, cfill, pk);
    pass2<<<NBUK, 256, 0, stream>>>(pk, coff, epk, off, cnt_nr);
    l1_fused<<<NN / 16, 256, 0, stream>>>(x, epk, off, cnt_nr, W1, root1, b1, h);
    l2_fused<<<NN / 8, 256, 0, stream>>>(h, epk, off, cnt_nr, W2, root2, b2, out);
}

// Round 8
// 539.279 us; speedup vs baseline: 2.1454x; 2.1326x over previous
//
#include <hip/hip_runtime.h>

#define NN 100000
#define NE 3200000
#define NR 8
#define NBUK 6250            // dst>>4 buckets (16 nodes each)
#define NXCD 8               // cells per bucket = one per XCD (blockIdx % 8)
#define NC2 (NBUK * NXCD)    // 50000 cells
#define SCAN_TPB 256
#define SCAN_EPB 1024
#define NB2 ((NC2 + SCAN_EPB - 1) / SCAN_EPB)   // 49 blocks

// ---------- XCD-chunked histogram: cell = (dst>>4)*8 + (blockIdx&7) ----------
__global__ void chunk_hist(const int* __restrict__ dst, int* __restrict__ ccnt) {
    int e = blockIdx.x * blockDim.x + threadIdx.x;
    if (e < NE) {
        int cell = (dst[e] >> 4) * NXCD + (blockIdx.x & (NXCD - 1));
        atomicAdd(&ccnt[cell], 1);
    }
}

// ---------- 3-kernel exclusive scan over ccnt[NC2] -> coff[NC2] ----------
__global__ void block_sums(const int* __restrict__ cnt, int* __restrict__ bsum) {
    __shared__ int s[SCAN_TPB];
    int base = blockIdx.x * SCAN_EPB;
    int t = threadIdx.x;
    int v = 0;
#pragma unroll
    for (int j = 0; j < 4; j++) {
        int idx = base + t * 4 + j;
        if (idx < NC2) v += cnt[idx];
    }
    s[t] = v; __syncthreads();
    for (int o = SCAN_TPB / 2; o > 0; o >>= 1) {
        if (t < o) s[t] += s[t + o];
        __syncthreads();
    }
    if (t == 0) bsum[blockIdx.x] = s[0];
}

__global__ void scan_sums(int* __restrict__ bsum) {  // single block, 1024 threads
    __shared__ int s[1024];
    int t = threadIdx.x;
    int v = (t < NB2) ? bsum[t] : 0;
    s[t] = v; __syncthreads();
    for (int o = 1; o < 1024; o <<= 1) {
        int u = (t >= o) ? s[t - o] : 0;
        __syncthreads();
        s[t] += u;
        __syncthreads();
    }
    if (t < NB2) bsum[t] = s[t] - v;  // exclusive
}

__global__ void block_scan(const int* __restrict__ cnt, const int* __restrict__ bsum,
                           int* __restrict__ off) {
    __shared__ int s[SCAN_TPB];
    int base = blockIdx.x * SCAN_EPB;
    int t = threadIdx.x;
    int v[4]; int sum = 0;
#pragma unroll
    for (int j = 0; j < 4; j++) {
        int idx = base + t * 4 + j;
        v[j] = (idx < NC2) ? cnt[idx] : 0;
        sum += v[j];
    }
    s[t] = sum; __syncthreads();
    int mine = sum;
    for (int o = 1; o < SCAN_TPB; o <<= 1) {
        int u = (t >= o) ? s[t - o] : 0;
        __syncthreads();
        s[t] += u;
        __syncthreads();
    }
    int ex = s[t] - mine + bsum[blockIdx.x];
#pragma unroll
    for (int j = 0; j < 4; j++) {
        int idx = base + t * 4 + j;
        if (idx < NC2) { off[idx] = ex; ex += v[j]; }
    }
}

// ---------- pass 1: scatter packed (dst&15)<<20 | et<<17 | src into XCD-pure cells ----
__global__ void pass1(const int* __restrict__ src, const int* __restrict__ dst,
                      const int* __restrict__ et, const int* __restrict__ coff,
                      int* __restrict__ cfill, unsigned* __restrict__ pk) {
    int e = blockIdx.x * blockDim.x + threadIdx.x;
    if (e >= NE) return;
    int d = dst[e];
    int cell = (d >> 4) * NXCD + (blockIdx.x & (NXCD - 1));
    int pos = coff[cell] + atomicAdd(&cfill[cell], 1);
    pk[pos] = ((unsigned)(d & 15) << 20) | ((unsigned)et[e] << 17) | (unsigned)src[e];
}

// ---------- pass 2: per-bucket fine sort by node; epk + CSR off + (node,rel) counts ----
__global__ __launch_bounds__(256) void pass2(const unsigned* __restrict__ pk,
                                             const int* __restrict__ coff,
                                             unsigned* __restrict__ epk,
                                             int* __restrict__ off,
                                             int* __restrict__ cnt_nr) {
    __shared__ int lcnt2[16][NR];
    __shared__ int lrow[16];
    __shared__ int lfill[16];
    __shared__ int lscan[16];
    int b = blockIdx.x, t = threadIdx.x;
    int base = coff[b * NXCD];
    int end = (b == NBUK - 1) ? NE : coff[(b + 1) * NXCD];
    if (t < 128) lcnt2[t >> 3][t & 7] = 0;
    if (t < 16) lfill[t] = 0;
    __syncthreads();
    for (int e = base + t; e < end; e += 256) {
        unsigned u = pk[e];
        atomicAdd(&lcnt2[u >> 20][(u >> 17) & 7], 1);
    }
    __syncthreads();
    if (t < 16) {
        int s = 0;
#pragma unroll
        for (int r = 0; r < NR; r++) s += lcnt2[t][r];
        lrow[t] = s;
    }
    if (t < 128) cnt_nr[b * 128 + t] = lcnt2[t >> 3][t & 7];
    __syncthreads();
    if (t == 0) {
        int run = 0;
        for (int d = 0; d < 16; d++) {
            lscan[d] = run;
            off[b * 16 + d] = base + run;
            run += lrow[d];
        }
        if (b == NBUK - 1) off[NN] = NE;
    }
    __syncthreads();
    for (int e = base + t; e < end; e += 256) {
        unsigned u = pk[e];
        int d = u >> 20;
        int p = atomicAdd(&lfill[d], 1);
        epk[base + lscan[d] + p] = u;
    }
}

// ---------- Layer 1 fused (round-5 form): gather + predicated rel-accumulate ----------
// block = 256 threads = 16 nodes x 16 feature-lanes
__global__ __launch_bounds__(256, 8) void l1_fused(
        const float* __restrict__ x, const unsigned* __restrict__ epk,
        const int* __restrict__ off, const int* __restrict__ cnt_nr,
        const float* __restrict__ W1, const float* __restrict__ root1,
        const float* __restrict__ b1, float* __restrict__ h) {
    __shared__ float sAgg[16][NR * 16 + 8];
    int nl = threadIdx.x >> 4, k = threadIdx.x & 15;
    int i = blockIdx.x * 16 + nl;
    int s0 = off[i], e1 = off[i + 1];

    float acc[NR];
#pragma unroll
    for (int r = 0; r < NR; r++) acc[r] = 0.0f;

    for (int e0 = s0; e0 < e1; e0 += 4) {
        unsigned u0 = epk[min(e0 + 0, NE - 1)];
        unsigned u1 = epk[min(e0 + 1, NE - 1)];
        unsigned u2 = epk[min(e0 + 2, NE - 1)];
        unsigned u3 = epk[min(e0 + 3, NE - 1)];
        float v0 = x[(u0 & 0x1FFFF) * 16 + k];
        float v1 = x[(u1 & 0x1FFFF) * 16 + k];
        float v2 = x[(u2 & 0x1FFFF) * 16 + k];
        float v3 = x[(u3 & 0x1FFFF) * 16 + k];
        int r0 = (u0 >> 17) & 7, r1 = (u1 >> 17) & 7;
        int r2 = (u2 >> 17) & 7, r3 = (u3 >> 17) & 7;
        bool m0 = e0 + 0 < e1, m1 = e0 + 1 < e1, m2 = e0 + 2 < e1, m3 = e0 + 3 < e1;
        v0 = m0 ? v0 : 0.0f; v1 = m1 ? v1 : 0.0f;
        v2 = m2 ? v2 : 0.0f; v3 = m3 ? v3 : 0.0f;
#pragma unroll
        for (int r = 0; r < NR; r++) {
            acc[r] += (r0 == r ? v0 : 0.0f);
            acc[r] += (r1 == r ? v1 : 0.0f);
            acc[r] += (r2 == r ? v2 : 0.0f);
            acc[r] += (r3 == r ? v3 : 0.0f);
        }
    }
#pragma unroll
    for (int r = 0; r < NR; r++) {
        int c = cnt_nr[i * 8 + r];
        sAgg[nl][r * 16 + k] = acc[r] * (1.0f / (float)(c > 1 ? c : 1));
    }
    __syncthreads();
    // 512 outputs (16 nodes x 32), 2 per thread; W1/root1/b1 via L1 (hot)
#pragma unroll
    for (int ph = 0; ph < 2; ph++) {
        int idx = ph * 256 + threadIdx.x;
        int n2 = idx >> 5, o = idx & 31;
        int ii = blockIdx.x * 16 + n2;
        float a = b1[o];
        const float* xi = x + ii * 16;
#pragma unroll
        for (int kk = 0; kk < 16; kk++) a += xi[kk] * root1[kk * 32 + o];
#pragma unroll
        for (int r = 0; r < NR; r++)
#pragma unroll
            for (int kk = 0; kk < 16; kk++)
                a += sAgg[n2][r * 16 + kk] * W1[(r * 16 + kk) * 32 + o];
        h[ii * 32 + o] = fmaxf(a, 0.0f);
    }
}

// ---------- Layer 2 fused (round-5 form): gather + predicated rel-accumulate ----------
// block = 256 threads = 8 nodes x 32 feature-lanes
__global__ __launch_bounds__(256, 8) void l2_fused(
        const float* __restrict__ h, const unsigned* __restrict__ epk,
        const int* __restrict__ off, const int* __restrict__ cnt_nr,
        const float* __restrict__ W2, const float* __restrict__ root2,
        const float* __restrict__ b2, float* __restrict__ out) {
    __shared__ float sAgg[8][NR * 32 + 1];
    int nl = threadIdx.x >> 5, k = threadIdx.x & 31;
    int i = blockIdx.x * 8 + nl;
    int s0 = off[i], e1 = off[i + 1];

    float acc[NR];
#pragma unroll
    for (int r = 0; r < NR; r++) acc[r] = 0.0f;

    for (int e0 = s0; e0 < e1; e0 += 4) {
        unsigned u0 = epk[min(e0 + 0, NE - 1)];
        unsigned u1 = epk[min(e0 + 1, NE - 1)];
        unsigned u2 = epk[min(e0 + 2, NE - 1)];
        unsigned u3 = epk[min(e0 + 3, NE - 1)];
        float v0 = h[(u0 & 0x1FFFF) * 32 + k];
        float v1 = h[(u1 & 0x1FFFF) * 32 + k];
        float v2 = h[(u2 & 0x1FFFF) * 32 + k];
        float v3 = h[(u3 & 0x1FFFF) * 32 + k];
        int r0 = (u0 >> 17) & 7, r1 = (u1 >> 17) & 7;
        int r2 = (u2 >> 17) & 7, r3 = (u3 >> 17) & 7;
        bool m0 = e0 + 0 < e1, m1 = e0 + 1 < e1, m2 = e0 + 2 < e1, m3 = e0 + 3 < e1;
        v0 = m0 ? v0 : 0.0f; v1 = m1 ? v1 : 0.0f;
        v2 = m2 ? v2 : 0.0f; v3 = m3 ? v3 : 0.0f;
#pragma unroll
        for (int r = 0; r < NR; r++) {
            acc[r] += (r0 == r ? v0 : 0.0f);
            acc[r] += (r1 == r ? v1 : 0.0f);
            acc[r] += (r2 == r ? v2 : 0.0f);
            acc[r] += (r3 == r ? v3 : 0.0f);
        }
    }
#pragma unroll
    for (int r = 0; r < NR; r++) {
        int c = cnt_nr[i * 8 + r];
        sAgg[nl][r * 32 + k] = acc[r] * (1.0f / (float)(c > 1 ? c : 1));
    }
    __syncthreads();
    // per node: 16 outputs, k-sum split across lane halves; W2/root2/b2 via L1
    int o = k & 15, half = k >> 4;
    float a = 0.0f;
    const float* hi = h + i * 32;
#pragma unroll
    for (int kk = 0; kk < 16; kk++) {
        int kf = half * 16 + kk;
        a += hi[kf] * root2[kf * 16 + o];
    }
#pragma unroll
    for (int r = 0; r < NR; r++)
#pragma unroll
        for (int kk = 0; kk < 16; kk++) {
            int kf = half * 16 + kk;
            a += sAgg[nl][r * 32 + kf] * W2[(r * 32 + kf) * 16 + o];
        }
    float tot = a + __shfl_xor(a, 16);
    if (half == 0) out[i * 16 + o] = tot + b2[o];
}

extern "C" void kernel_launch(void* const* d_in, const int* in_sizes, int n_in,
                              void* d_out, int out_size, void* d_ws, size_t ws_size,
                              hipStream_t stream) {
    const float* x = (const float*)d_in[0];
    const int* ei = (const int*)d_in[1];
    const int* et = (const int*)d_in[2];
    const float* W1 = (const float*)d_in[3];
    const float* root1 = (const float*)d_in[4];
    const float* b1 = (const float*)d_in[5];
    const float* W2 = (const float*)d_in[6];
    const float* root2 = (const float*)d_in[7];
    const float* b2 = (const float*)d_in[8];
    float* out = (float*)d_out;
    const int* src = ei;
    const int* dst = ei + NE;

    char* ws = (char*)d_ws;
    int* off       = (int*)(ws + 0);             // (NN+1)*4 = 400,004 B
    int* ccnt      = (int*)(ws + 400016);        // 200 KB
    int* cfill     = (int*)(ws + 600016);        // 200 KB
    int* coff      = (int*)(ws + 800016);        // 200 KB
    int* bsum      = (int*)(ws + 1000032);       // ~200 B
    unsigned* pk   = (unsigned*)(ws + 1004096);  // 12.8 MB
    unsigned* epk  = (unsigned*)(ws + 13804096); // 12.8 MB
    float* h       = (float*)(ws + 26604096);    // 12.8 MB
    int* cnt_nr    = (int*)(ws + 39404096);      // 3.2 MB  (total ~42.6 MB)

    const int TPB = 256;
    hipMemsetAsync(ccnt, 0, 400000, stream);   // ccnt + cfill (contiguous)
    chunk_hist<<<(NE + TPB - 1) / TPB, TPB, 0, stream>>>(dst, ccnt);
    block_sums<<<NB2, SCAN_TPB, 0, stream>>>(ccnt, bsum);
    scan_sums<<<1, 1024, 0, stream>>>(bsum);
    block_scan<<<NB2, SCAN_TPB, 0, stream>>>(ccnt, bsum, coff);
    pass1<<<(NE + TPB - 1) / TPB, TPB, 0, stream>>>(src, dst, et, coff, cfill, pk);
    pass2<<<NBUK, 256, 0, stream>>>(pk, coff, epk, off, cnt_nr);
    l1_fused<<<NN / 16, 256, 0, stream>>>(x, epk, off, cnt_nr, W1, root1, b1, h);
    l2_fused<<<NN / 8, 256, 0, stream>>>(h, epk, off, cnt_nr, W2, root2, b2, out);
}

// Round 9
// 312.167 us; speedup vs baseline: 3.7062x; 1.7275x over previous
//
#include <hip/hip_runtime.h>

#define NN 100000
#define NE 3200000
#define NR 8
#define NREG 391             // ceil(NN/256) regions of 256 nodes
#define EPB 4096             // edges per pass1a block
#define NBLKA ((NE + EPB - 1) / EPB)   // 782
#define CAP 12288            // pass1b region capacity (lambda~8184, +45 sigma)

// ---------- hist391: LDS-staged region histogram ----------
__global__ __launch_bounds__(256) void hist391(const int* __restrict__ dst,
                                               int* __restrict__ ghist) {
    __shared__ int lh[NREG];
    int t = threadIdx.x;
    for (int i = t; i < NREG; i += 256) lh[i] = 0;
    __syncthreads();
    int base = blockIdx.x * EPB;
#pragma unroll
    for (int i = 0; i < EPB / 256; i++) {
        int e = base + i * 256 + t;
        if (e < NE) atomicAdd(&lh[dst[e] >> 8], 1);
    }
    __syncthreads();
    for (int i = t; i < NREG; i += 256)
        if (lh[i]) atomicAdd(&ghist[i], lh[i]);
}

// ---------- scan391: exclusive scan of region counts -> rbase, gfill ----------
__global__ __launch_bounds__(512) void scan391(const int* __restrict__ ghist,
                                               int* __restrict__ rbase,
                                               int* __restrict__ gfill,
                                               int* __restrict__ off) {
    __shared__ int s[512];
    int t = threadIdx.x;
    int v = (t < NREG) ? ghist[t] : 0;
    s[t] = v; __syncthreads();
    for (int o = 1; o < 512; o <<= 1) {
        int u = (t >= o) ? s[t - o] : 0;
        __syncthreads();
        s[t] += u;
        __syncthreads();
    }
    if (t < NREG) { int ex = s[t] - v; rbase[t] = ex; gfill[t] = ex; }
    if (t == 0) off[NN] = NE;
}

// ---------- pass1a: LDS-staged region binning (no per-edge global atomics) ----------
__global__ __launch_bounds__(256) void pass1a(const int* __restrict__ src,
                                              const int* __restrict__ dst,
                                              const int* __restrict__ et,
                                              int* __restrict__ gfill,
                                              unsigned* __restrict__ pk) {
    __shared__ unsigned sPk[EPB];
    __shared__ unsigned sMeta[EPB];   // bin<<12 | rank
    __shared__ int lh[NREG];
    __shared__ int gb[NREG];
    int t = threadIdx.x;
    for (int i = t; i < NREG; i += 256) lh[i] = 0;
    __syncthreads();
    int base = blockIdx.x * EPB;
#pragma unroll
    for (int i = 0; i < EPB / 256; i++) {
        int s2 = i * 256 + t;
        int e = base + s2;
        if (e < NE) {
            int d = dst[e];
            int bin = d >> 8;
            int rank = atomicAdd(&lh[bin], 1);
            sPk[s2] = ((unsigned)(d & 255) << 20) | ((unsigned)et[e] << 17) | (unsigned)src[e];
            sMeta[s2] = ((unsigned)bin << 12) | (unsigned)rank;
        } else {
            sMeta[s2] = 0xFFFFFFFFu;
        }
    }
    __syncthreads();
    for (int i = t; i < NREG; i += 256)
        gb[i] = lh[i] ? atomicAdd(&gfill[i], lh[i]) : 0;
    __syncthreads();
#pragma unroll
    for (int i = 0; i < EPB / 256; i++) {
        int s2 = i * 256 + t;
        unsigned m = sMeta[s2];
        if (m != 0xFFFFFFFFu) {
            int bin = m >> 12;
            int rank = m & 4095;
            pk[gb[bin] + rank] = sPk[s2];
        }
    }
}

// ---------- pass1b: per-region LDS sort to (node,rel); writes epk + off + cnt_nr ----
__global__ __launch_bounds__(1024, 1) void pass1b(const unsigned* __restrict__ pk,
                                                  const int* __restrict__ rbase,
                                                  const int* __restrict__ ghist,
                                                  unsigned* __restrict__ epk,
                                                  int* __restrict__ off,
                                                  int* __restrict__ cnt_nr) {
    __shared__ unsigned sSorted[CAP];    // 48 KB
    __shared__ int lh[2048];             // 8 KB  (node,rel) counts
    __shared__ int lbase[2048];          // 8 KB
    __shared__ int sc[1024];             // 4 KB scan temp
    int b = blockIdx.x, t = threadIdx.x;
    int base = rbase[b];
    int cnt = ghist[b];
    for (int i = t; i < 2048; i += 1024) lh[i] = 0;
    __syncthreads();
    unsigned pkr[CAP / 1024];
    unsigned meta[CAP / 1024];
#pragma unroll
    for (int i = 0; i < CAP / 1024; i++) {
        int idx = i * 1024 + t;
        if (idx < cnt) {
            unsigned u = pk[base + idx];
            int bin = (int)(u >> 20) * 8 + (int)((u >> 17) & 7);
            int rank = atomicAdd(&lh[bin], 1);
            pkr[i] = u;
            meta[i] = ((unsigned)bin << 14) | (unsigned)rank;
        } else {
            meta[i] = 0xFFFFFFFFu;
        }
    }
    __syncthreads();
    // scan 2048 bins with 1024 threads (2 per thread)
    int c0 = lh[t * 2], c1 = lh[t * 2 + 1];
    int s2 = c0 + c1;
    sc[t] = s2; __syncthreads();
    for (int o = 1; o < 1024; o <<= 1) {
        int u = (t >= o) ? sc[t - o] : 0;
        __syncthreads();
        sc[t] += u;
        __syncthreads();
    }
    int ex = sc[t] - s2;
    lbase[t * 2] = ex;
    lbase[t * 2 + 1] = ex + c0;
    __syncthreads();
    // outputs: CSR off + per-(node,rel) counts
    int nn = NN - b * 256; if (nn > 256) nn = 256;
    if (t < nn) off[b * 256 + t] = base + lbase[t * 8];
    for (int i = t; i < nn * 8; i += 1024) cnt_nr[b * 2048 + i] = lh[i];
    __syncthreads();
    // in-LDS scatter
#pragma unroll
    for (int i = 0; i < CAP / 1024; i++) {
        unsigned m = meta[i];
        if (m != 0xFFFFFFFFu)
            sSorted[lbase[m >> 14] + (m & 16383)] = pkr[i];
    }
    __syncthreads();
    // coalesced write-out
#pragma unroll
    for (int i = 0; i < CAP / 1024; i++) {
        int idx = i * 1024 + t;
        if (idx < cnt) epk[base + idx] = sSorted[idx];
    }
}

// ---------- Layer 1 fused (unchanged from round 8) ----------
__global__ __launch_bounds__(256, 8) void l1_fused(
        const float* __restrict__ x, const unsigned* __restrict__ epk,
        const int* __restrict__ off, const int* __restrict__ cnt_nr,
        const float* __restrict__ W1, const float* __restrict__ root1,
        const float* __restrict__ b1, float* __restrict__ h) {
    __shared__ float sAgg[16][NR * 16 + 8];
    int nl = threadIdx.x >> 4, k = threadIdx.x & 15;
    int i = blockIdx.x * 16 + nl;
    int s0 = off[i], e1 = off[i + 1];

    float acc[NR];
#pragma unroll
    for (int r = 0; r < NR; r++) acc[r] = 0.0f;

    for (int e0 = s0; e0 < e1; e0 += 4) {
        unsigned u0 = epk[min(e0 + 0, NE - 1)];
        unsigned u1 = epk[min(e0 + 1, NE - 1)];
        unsigned u2 = epk[min(e0 + 2, NE - 1)];
        unsigned u3 = epk[min(e0 + 3, NE - 1)];
        float v0 = x[(u0 & 0x1FFFF) * 16 + k];
        float v1 = x[(u1 & 0x1FFFF) * 16 + k];
        float v2 = x[(u2 & 0x1FFFF) * 16 + k];
        float v3 = x[(u3 & 0x1FFFF) * 16 + k];
        int r0 = (u0 >> 17) & 7, r1 = (u1 >> 17) & 7;
        int r2 = (u2 >> 17) & 7, r3 = (u3 >> 17) & 7;
        bool m0 = e0 + 0 < e1, m1 = e0 + 1 < e1, m2 = e0 + 2 < e1, m3 = e0 + 3 < e1;
        v0 = m0 ? v0 : 0.0f; v1 = m1 ? v1 : 0.0f;
        v2 = m2 ? v2 : 0.0f; v3 = m3 ? v3 : 0.0f;
#pragma unroll
        for (int r = 0; r < NR; r++) {
            acc[r] += (r0 == r ? v0 : 0.0f);
            acc[r] += (r1 == r ? v1 : 0.0f);
            acc[r] += (r2 == r ? v2 : 0.0f);
            acc[r] += (r3 == r ? v3 : 0.0f);
        }
    }
#pragma unroll
    for (int r = 0; r < NR; r++) {
        int c = cnt_nr[i * 8 + r];
        sAgg[nl][r * 16 + k] = acc[r] * (1.0f / (float)(c > 1 ? c : 1));
    }
    __syncthreads();
#pragma unroll
    for (int ph = 0; ph < 2; ph++) {
        int idx = ph * 256 + threadIdx.x;
        int n2 = idx >> 5, o = idx & 31;
        int ii = blockIdx.x * 16 + n2;
        float a = b1[o];
        const float* xi = x + ii * 16;
#pragma unroll
        for (int kk = 0; kk < 16; kk++) a += xi[kk] * root1[kk * 32 + o];
#pragma unroll
        for (int r = 0; r < NR; r++)
#pragma unroll
            for (int kk = 0; kk < 16; kk++)
                a += sAgg[n2][r * 16 + kk] * W1[(r * 16 + kk) * 32 + o];
        h[ii * 32 + o] = fmaxf(a, 0.0f);
    }
}

// ---------- Layer 2 fused (unchanged from round 8) ----------
__global__ __launch_bounds__(256, 8) void l2_fused(
        const float* __restrict__ h, const unsigned* __restrict__ epk,
        const int* __restrict__ off, const int* __restrict__ cnt_nr,
        const float* __restrict__ W2, const float* __restrict__ root2,
        const float* __restrict__ b2, float* __restrict__ out) {
    __shared__ float sAgg[8][NR * 32 + 1];
    int nl = threadIdx.x >> 5, k = threadIdx.x & 31;
    int i = blockIdx.x * 8 + nl;
    int s0 = off[i], e1 = off[i + 1];

    float acc[NR];
#pragma unroll
    for (int r = 0; r < NR; r++) acc[r] = 0.0f;

    for (int e0 = s0; e0 < e1; e0 += 4) {
        unsigned u0 = epk[min(e0 + 0, NE - 1)];
        unsigned u1 = epk[min(e0 + 1, NE - 1)];
        unsigned u2 = epk[min(e0 + 2, NE - 1)];
        unsigned u3 = epk[min(e0 + 3, NE - 1)];
        float v0 = h[(u0 & 0x1FFFF) * 32 + k];
        float v1 = h[(u1 & 0x1FFFF) * 32 + k];
        float v2 = h[(u2 & 0x1FFFF) * 32 + k];
        float v3 = h[(u3 & 0x1FFFF) * 32 + k];
        int r0 = (u0 >> 17) & 7, r1 = (u1 >> 17) & 7;
        int r2 = (u2 >> 17) & 7, r3 = (u3 >> 17) & 7;
        bool m0 = e0 + 0 < e1, m1 = e0 + 1 < e1, m2 = e0 + 2 < e1, m3 = e0 + 3 < e1;
        v0 = m0 ? v0 : 0.0f; v1 = m1 ? v1 : 0.0f;
        v2 = m2 ? v2 : 0.0f; v3 = m3 ? v3 : 0.0f;
#pragma unroll
        for (int r = 0; r < NR; r++) {
            acc[r] += (r0 == r ? v0 : 0.0f);
            acc[r] += (r1 == r ? v1 : 0.0f);
            acc[r] += (r2 == r ? v2 : 0.0f);
            acc[r] += (r3 == r ? v3 : 0.0f);
        }
    }
#pragma unroll
    for (int r = 0; r < NR; r++) {
        int c = cnt_nr[i * 8 + r];
        sAgg[nl][r * 32 + k] = acc[r] * (1.0f / (float)(c > 1 ? c : 1));
    }
    __syncthreads();
    int o = k & 15, half = k >> 4;
    float a = 0.0f;
    const float* hi = h + i * 32;
#pragma unroll
    for (int kk = 0; kk < 16; kk++) {
        int kf = half * 16 + kk;
        a += hi[kf] * root2[kf * 16 + o];
    }
#pragma unroll
    for (int r = 0; r < NR; r++)
#pragma unroll
        for (int kk = 0; kk < 16; kk++) {
            int kf = half * 16 + kk;
            a += sAgg[nl][r * 32 + kf] * W2[(r * 32 + kf) * 16 + o];
        }
    float tot = a + __shfl_xor(a, 16);
    if (half == 0) out[i * 16 + o] = tot + b2[o];
}

extern "C" void kernel_launch(void* const* d_in, const int* in_sizes, int n_in,
                              void* d_out, int out_size, void* d_ws, size_t ws_size,
                              hipStream_t stream) {
    const float* x = (const float*)d_in[0];
    const int* ei = (const int*)d_in[1];
    const int* et = (const int*)d_in[2];
    const float* W1 = (const float*)d_in[3];
    const float* root1 = (const float*)d_in[4];
    const float* b1 = (const float*)d_in[5];
    const float* W2 = (const float*)d_in[6];
    const float* root2 = (const float*)d_in[7];
    const float* b2 = (const float*)d_in[8];
    float* out = (float*)d_out;
    const int* src = ei;
    const int* dst = ei + NE;

    char* ws = (char*)d_ws;
    int* off       = (int*)(ws + 0);             // (NN+1)*4 = 400,004 B
    int* ghist     = (int*)(ws + 400064);        // 391*4
    int* rbase     = (int*)(ws + 401664);        // 391*4
    int* gfill     = (int*)(ws + 403264);        // 391*4
    unsigned* pk   = (unsigned*)(ws + 404864);   // 12.8 MB
    unsigned* epk  = (unsigned*)(ws + 13204864); // 12.8 MB
    float* h       = (float*)(ws + 26004864);    // 12.8 MB
    int* cnt_nr    = (int*)(ws + 38804864);      // 3.2 MB  (total ~42 MB)

    hipMemsetAsync(ghist, 0, NREG * sizeof(int), stream);
    hist391<<<NBLKA, 256, 0, stream>>>(dst, ghist);
    scan391<<<1, 512, 0, stream>>>(ghist, rbase, gfill, off);
    pass1a<<<NBLKA, 256, 0, stream>>>(src, dst, et, gfill, pk);
    pass1b<<<NREG, 1024, 0, stream>>>(pk, rbase, ghist, epk, off, cnt_nr);
    l1_fused<<<NN / 16, 256, 0, stream>>>(x, epk, off, cnt_nr, W1, root1, b1, h);
    l2_fused<<<NN / 8, 256, 0, stream>>>(h, epk, off, cnt_nr, W2, root2, b2, out);
}